// Round 20
// baseline (543.043 us; speedup 1.0000x reference)
//
#include <hip/hip_runtime.h>
#include <cmath>

using f16x8 = __attribute__((ext_vector_type(8))) _Float16;
using f32x4 = __attribute__((ext_vector_type(4))) float;

// ---------- helpers ----------
__device__ __forceinline__ void gld16(void* lds, const void* g) {
    __builtin_amdgcn_global_load_lds(
        (const __attribute__((address_space(1))) unsigned int*)g,
        (__attribute__((address_space(3))) unsigned int*)lds, 16, 0, 0);
}

// ========= Layouts =========
// f16 2-product split: x = hi + lo (f16);  proj = hi*w + lo*w, W single f16.
// A-blob (LDS-staged): per (mt128, kt) 16KB: 128 m-rows x 128B, hi/lo planes;
//   slot s = isLo*4 + q stored at s ^ (r&7) (0-conflict proven).  kt stride 34.
// W-blob (global->reg, k-major granules): granule (g, qg, u) = 16B holding
//   f16 W[qg*8+e][u], e=0..7.  addr = ((g*136 + qg)*1024 + u)*16.
//   qg = 0..127 real (pad to 136 for kt+2 prefetch).  A wave's fragment load
//   (16 consecutive u per lane-group) = 4 x 256B contiguous segments.

// ---------- convert x -> A blob ----------
__global__ __launch_bounds__(256)
void bru_conv_a(const float* __restrict__ x, char* __restrict__ Ablob,
                int T, int D, int Tc, int t0, int Mc)
{
    const int gid = blockIdx.x * 256 + threadIdx.x;   // Mc*32 threads
    const int kt = gid / Mc;
    const int m  = gid - kt * Mc;
    const int mt = m >> 7, row = m & 127;

    const long xrow = (long)(m / Tc) * T + t0 + (m % Tc);
    const float* src = x + xrow * (long)D + kt * 32;

    float v[32];
    #pragma unroll
    for (int i = 0; i < 8; ++i)
        *(float4*)&v[i * 4] = *(const float4*)(src + i * 4);

    _Float16 hi[32], lo[32];
    #pragma unroll
    for (int k = 0; k < 32; ++k) {
        hi[k] = (_Float16)v[k];
        lo[k] = (_Float16)(v[k] - (float)hi[k]);
    }

    char* base = Ablob + ((size_t)(mt * 34 + kt)) * 16384 + (size_t)row * 128;
    #pragma unroll
    for (int q = 0; q < 4; ++q) {
        _Float16 oh[8], ol[8];
        #pragma unroll
        for (int j = 0; j < 8; ++j) { oh[j] = hi[q * 8 + j]; ol[j] = lo[q * 8 + j]; }
        *(f16x8*)(base + (((q    ) ^ (row & 7)) << 4)) = *(f16x8*)oh;
        *(f16x8*)(base + (((q + 4) ^ (row & 7)) << 4)) = *(f16x8*)ol;
    }
}

// ---------- convert W (3 gates) -> k-major granule blob ----------
__global__ __launch_bounds__(256)
void bru_conv_w(const float* __restrict__ wz, const float* __restrict__ wr,
                const float* __restrict__ wh, char* __restrict__ Wblob,
                int D, int U)
{
    const int gid = blockIdx.x * 256 + threadIdx.x;   // 3*128*1024 threads
    const int g    = gid >> 17;
    const int rest = gid & 131071;
    const int qg   = rest >> 10;          // k-octet 0..127
    const int u    = rest & 1023;         // consecutive -> coalesced

    const float* W = (g == 0) ? wz : (g == 1) ? wr : wh;

    _Float16 o[8];
    #pragma unroll
    for (int e = 0; e < 8; ++e)
        o[e] = (_Float16)W[(long)(qg * 8 + e) * U + u];

    *(f16x8*)(Wblob + (((size_t)(g * 136 + qg) << 10) + u) * 16) = *(f16x8*)o;
}

// ---------- f16 2-product MFMA GEMM: A via LDS, B global->reg ----------
// Block tile 128x256, 256 threads = 4 waves 2x2 (wave tile 64m x 128n),
// 16x16x32_f16.  LDS 32KB: A 2x16KB double buffer.  B fragments loaded
// straight from the L2/L3-resident k-major blob into an even/odd register
// pair, prefetched one full kt ahead.  LDS/block-kt drops 96KB -> 48KB
// (<< MFMA 1242 cyc), so the 2 independent blocks/CU reach MFMA-bound.
__global__ __launch_bounds__(256, 2)
void bru_gemm_mfma(const char* __restrict__ Ablob, const char* __restrict__ Wblob,
                   const float* __restrict__ bz, const float* __restrict__ br,
                   const float* __restrict__ bh,
                   _Float16* __restrict__ proj,
                   int nmt, int U, int Mc)
{
    __shared__ char sm[32768];   // A: 2x16KB

    const int ngrid = gridDim.x;
    const int bid   = blockIdx.x;
    int lid = bid;
    if ((ngrid & 7) == 0) lid = (bid & 7) * (ngrid >> 3) + (bid >> 3);
    const int mt  = lid / 12;
    const int rem = lid - mt * 12;
    const int g   = rem >> 2;
    const int nt  = rem & 3;

    const int tid  = threadIdx.x;
    const int lane = tid & 63;
    const int w    = tid >> 6;
    const int wm   = w >> 1, wn = w & 1;   // 2x2 wave grid; wave tile 64x128
    const int l15  = lane & 15;
    const int lgrp = lane >> 4;

    const char* asrc = Ablob + (size_t)(mt * 34) * 16384;
    const int st = tid * 16;

    const int abase = (wm * 64 + l15) * 128;           // + f*2048, f=0..3
    const int slotA = (lgrp ^ (l15 & 7)) << 4;         // lo at ^64

    // B: per-lane base at (gate, u0 = nt*256 + wn*128 + l15)
    const char* bptr = Wblob + (((size_t)(g * 136) << 10)
                                + (size_t)(nt * 256 + wn * 128 + l15)) * 16;

    f32x4 acc[4][8];
    #pragma unroll
    for (int i = 0; i < 4; ++i)
        #pragma unroll
        for (int j = 0; j < 8; ++j) acc[i][j] = (f32x4)0.f;

    f16x8 Be[8], Bo[8];

#define STAGE_A(kt_, buf_) \
    _Pragma("unroll") for (int c_ = 0; c_ < 4; ++c_) \
        gld16(sm + (buf_) * 16384 + c_ * 4096 + st, \
              asrc + (size_t)(kt_) * 16384 + c_ * 4096 + st);

#define LOADB(dst, kt_) \
    _Pragma("unroll") for (int j_ = 0; j_ < 8; ++j_) \
        dst[j_] = *(const f16x8*)(bptr + ((((size_t)((kt_) * 4 + lgrp)) << 10) \
                                          + (size_t)(j_ * 16)) * 16);

#define COMPUTE(buf_, BB) do { \
    const char* sa_ = sm + (buf_) * 16384; \
    _Pragma("unroll") for (int f_ = 0; f_ < 4; ++f_) { \
        f16x8 ah_ = *(const f16x8*)(sa_ + abase + f_ * 2048 + slotA); \
        f16x8 al_ = *(const f16x8*)(sa_ + abase + f_ * 2048 + (slotA ^ 64)); \
        _Pragma("unroll") for (int j_ = 0; j_ < 8; ++j_) { \
            acc[f_][j_] = __builtin_amdgcn_mfma_f32_16x16x32_f16(ah_, BB[j_], acc[f_][j_], 0, 0, 0); \
            acc[f_][j_] = __builtin_amdgcn_mfma_f32_16x16x32_f16(al_, BB[j_], acc[f_][j_], 0, 0, 0); } } \
    } while (0)

    // prologue
    STAGE_A(0, 0);
    LOADB(Be, 0);
    __syncthreads();

    for (int kt2 = 0; kt2 < 16; ++kt2) {
        const int kt = 2 * kt2;

        STAGE_A(kt + 1, 1);        // buf1 <- kt+1
        LOADB(Bo, kt + 1);         // regs <- B(kt+1)
        COMPUTE(0, Be);            // uses buf0 (kt), B(kt)
        __syncthreads();

        STAGE_A(kt + 2, 0);        // buf0 <- kt+2 (kt=30: stages pad 32)
        LOADB(Be, kt + 2);         // qg pad to 136 covers kt=32
        COMPUTE(1, Bo);            // uses buf1 (kt+1), B(kt+1)
        __syncthreads();
    }
#undef STAGE_A
#undef LOADB
#undef COMPUTE

    // epilogue: C map (proven): col=lane&15, row=lgrp*4+reg
    const float* bias = (g == 0) ? bz : (g == 1) ? br : bh;
    const int n0 = nt * 256 + wn * 128;
    float bcol[8];
    #pragma unroll
    for (int j = 0; j < 8; ++j) bcol[j] = bias[n0 + j * 16 + l15];

    _Float16* cbase = proj + (size_t)g * Mc * U + (size_t)n0 + l15;
    #pragma unroll
    for (int f = 0; f < 4; ++f) {
        #pragma unroll
        for (int reg = 0; reg < 4; ++reg) {
            const int row = mt * 128 + wm * 64 + f * 16 + lgrp * 4 + reg;
            #pragma unroll
            for (int j = 0; j < 8; ++j)
                cbase[(size_t)row * U + j * 16] = (_Float16)(acc[f][j][reg] + bcol[j]);
        }
    }
}

// ---------- scan: one thread per (b,u); 8-deep rotating register prefetch ----------
#define PF 8
__global__ __launch_bounds__(256)
void bru_scan(const _Float16* __restrict__ proj,
              const float* __restrict__ mz, const float* __restrict__ mr,
              float* __restrict__ out,
              float* __restrict__ hstate,
              int B, int T, int U, int Tc, int t0, int Mc)
{
    const int idx = blockIdx.x * blockDim.x + threadIdx.x;
    const int b = idx / U;
    const int u = idx - b * U;

    float h = (t0 == 0) ? 0.f : hstate[idx];
    const float vmz = mz[u];
    const float vmr = mr[u];

    const _Float16* pz = proj + (long)b * Tc * U + u;
    const _Float16* pr = pz + (long)Mc * U;
    const _Float16* ph = pr + (long)Mc * U;
    float* po = out + ((long)b * T + t0) * U + u;

    _Float16 fz[PF], fr[PF], fh[PF];
    #pragma unroll
    for (int i = 0; i < PF; ++i) {
        const long o = (long)((i < Tc) ? i : (Tc - 1)) * U;
        fz[i] = pz[o]; fr[i] = pr[o]; fh[i] = ph[o];
    }

    for (int t = 0; t < Tc; t += PF) {
        #pragma unroll
        for (int i = 0; i < PF; ++i) {
            const float xz = (float)fz[i];
            const float xr = (float)fr[i];
            const float xh = (float)fh[i];
            {
                int tn = t + i + PF; if (tn > Tc - 1) tn = Tc - 1;
                const long o = (long)tn * U;
                fz[i] = pz[o]; fr[i] = pr[o]; fh[i] = ph[o];
            }
            const float e2r = __expf(2.f * (xr + h * vmr));
            const float rr  = 2.f - 2.f / (e2r + 1.f);             // tanh(.)+1
            const float zz  = 1.f / (1.f + __expf(-(xz + h * vmz)));
            const float e2h = __expf(2.f * (xh + rr * h));
            const float hh  = 1.f - 2.f / (e2h + 1.f);             // tanh(.)
            h = (1.f - zz) * hh + zz * h;
            if (t + i < Tc) po[(long)(t + i) * U] = h;
        }
    }
    hstate[idx] = h;
}

// ---------- launch ----------
extern "C" void kernel_launch(void* const* d_in, const int* in_sizes, int n_in,
                              void* d_out, int out_size, void* d_ws, size_t ws_size,
                              hipStream_t stream)
{
    const float* x  = (const float*)d_in[0];
    const float* wz = (const float*)d_in[1];
    const float* wr = (const float*)d_in[2];
    const float* wh = (const float*)d_in[3];
    const float* mz = (const float*)d_in[4];
    const float* mr = (const float*)d_in[5];
    const float* bz = (const float*)d_in[6];
    const float* br = (const float*)d_in[7];
    const float* bh = (const float*)d_in[8];

    const int B = 64, T = 512, D = 1024, U = 1024;

    const size_t h_bytes = (size_t)B * U * sizeof(float);
    const size_t w_bytes = (size_t)3 * 136 * 1024 * 16;   // 6.68 MB incl. qg pad

    int Tc = T;
    while (Tc > 4) {
        const int nmt_ = B * Tc / 128;
        const size_t a_bytes_ = (size_t)nmt_ * 34 * 16384;
        const size_t p_bytes_ = 3ull * B * Tc * U * sizeof(_Float16);
        if (h_bytes + w_bytes + a_bytes_ + p_bytes_ <= ws_size) break;
        Tc >>= 1;
    }
    const int nmt = B * Tc / 128;
    const int Mc  = B * Tc;
    const size_t a_bytes = (size_t)nmt * 34 * 16384;

    float*    h_state = (float*)d_ws;
    char*     Wblob   = (char*)d_ws + h_bytes;
    char*     Ablob   = (char*)d_ws + h_bytes + w_bytes;
    _Float16* proj    = (_Float16*)((char*)d_ws + h_bytes + w_bytes + a_bytes);

    bru_conv_w<<<3 * 128 * 1024 / 256, 256, 0, stream>>>(wz, wr, wh, Wblob, D, U);

    for (int t0 = 0; t0 < T; t0 += Tc) {
        bru_conv_a<<<(Mc * 32) / 256, 256, 0, stream>>>(x, Ablob, T, D, Tc, t0, Mc);

        bru_gemm_mfma<<<3 * nmt * 4, 256, 0, stream>>>(
            Ablob, Wblob, bz, br, bh, proj, nmt, U, Mc);

        bru_scan<<<(B * U) / 256, 256, 0, stream>>>(
            proj, mz, mr, (float*)d_out, h_state, B, T, U, Tc, t0, Mc);
    }
}